// Round 1
// 308.173 us; speedup vs baseline: 1.0043x; 1.0043x over previous
//
#include <hip/hip_runtime.h>
#include <math.h>
#include <stdint.h>

// FlowAttention B=4, L=S=4096, H=16, D=64 fp32.
// P1 ksum(K) -> P2 qsum,qn(Q) -> P3 kn,den,KV-partials via MFMA (K,V) -> reduce -> P4 out via MFMA (Q).
// GEMM-shaped contractions use bf16 hi/lo-split MFMA (3 mfma per tile-step, ~2^-16 rel err).
// R1: reg-prefetch pipelines in k_kv/k_out, KV atomics -> partial stores + k_reduce,
//     batched loads + occupancy bump in k_ksum/k_qpass.
#define B_ 4
#define L_ 4096
#define H_ 16
#define EPSF 1e-6f
#define STR 66   // k_kv LDS row stride (words)
#define STRO 68  // k_out LDS row stride (words, 16B-aligned rows)

typedef short bf16x8 __attribute__((ext_vector_type(8)));
typedef float f32x4 __attribute__((ext_vector_type(4)));
union FragU { uint32_t u[4]; bf16x8 v; };

__device__ __forceinline__ float sigf(float x) { return 1.0f / (1.0f + __expf(-x)); }

// pack fp32 -> (bf16 hi | bf16 lo) in one 32-bit word. hi = truncate-to-bf16, lo = x - hi.
__device__ __forceinline__ uint32_t packhl(float x) {
    uint32_t xb = __float_as_uint(x);
    uint32_t hb = xb & 0xFFFF0000u;
    float lo = x - __uint_as_float(hb);
    return (hb >> 16) | (__float_as_uint(lo) & 0xFFFF0000u);
}

// 8 packed words (k-order) -> hi and lo bf16x8 fragments via v_perm
__device__ __forceinline__ void buildfrag(const uint32_t w[8], bf16x8& hi, bf16x8& lo) {
    FragU H, L;
#pragma unroll
    for (int t = 0; t < 4; ++t) {
        H.u[t] = __builtin_amdgcn_perm(w[2 * t + 1], w[2 * t], 0x05040100u);
        L.u[t] = __builtin_amdgcn_perm(w[2 * t + 1], w[2 * t], 0x07060302u);
    }
    hi = H.v; lo = L.v;
}

#define MFMA3(acc, ahi, alo, bhi, blo)                                        \
    acc = __builtin_amdgcn_mfma_f32_16x16x32_bf16(ahi, bhi, acc, 0, 0, 0);    \
    acc = __builtin_amdgcn_mfma_f32_16x16x32_bf16(ahi, blo, acc, 0, 0, 0);    \
    acc = __builtin_amdgcn_mfma_f32_16x16x32_bf16(alo, bhi, acc, 0, 0, 0);

// ---------------- P1: ksum[d] = sum_s sigmoid(K) ----------------
__global__ __launch_bounds__(256, 8) void k_ksum(const float* __restrict__ K,
                                                 float* __restrict__ ksum) {
    int bh = blockIdx.x, b = bh >> 4, h = bh & 15;
    int t = threadIdx.x, lane = t & 63, w = t >> 6;
    int q4 = lane >> 4, i16 = lane & 15;
    int r0 = blockIdx.y * 128 + w * 32;
    float a0 = 0.f, a1 = 0.f, a2 = 0.f, a3 = 0.f;
#pragma unroll
    for (int ib = 0; ib < 2; ++ib) {
        float4 x[4];
#pragma unroll
        for (int j = 0; j < 4; ++j) {
            int r = r0 + (ib * 4 + j) * 4 + q4;
            x[j] = *(const float4*)(K + (((size_t)b * L_ + r) * H_ + h) * 64 + 4 * i16);
        }
#pragma unroll
        for (int j = 0; j < 4; ++j) {
            a0 += sigf(x[j].x); a1 += sigf(x[j].y);
            a2 += sigf(x[j].z); a3 += sigf(x[j].w);
        }
    }
#pragma unroll
    for (int m = 16; m < 64; m <<= 1) {
        a0 += __shfl_xor(a0, m, 64); a1 += __shfl_xor(a1, m, 64);
        a2 += __shfl_xor(a2, m, 64); a3 += __shfl_xor(a3, m, 64);
    }
    if (q4 == 0) {
        atomicAdd(&ksum[bh * 64 + 4 * i16 + 0], a0);
        atomicAdd(&ksum[bh * 64 + 4 * i16 + 1], a1);
        atomicAdd(&ksum[bh * 64 + 4 * i16 + 2], a2);
        atomicAdd(&ksum[bh * 64 + 4 * i16 + 3], a3);
    }
}

// ---------------- P2: qsum[d], qn[d] ----------------
__global__ __launch_bounds__(256, 6) void k_qpass(const float* __restrict__ Q,
                                                  const float* __restrict__ ksum,
                                                  float* __restrict__ qsum,
                                                  float* __restrict__ qn) {
    int bh = blockIdx.x, b = bh >> 4, h = bh & 15;
    int t = threadIdx.x, lane = t & 63, w = t >> 6;
    int q4 = lane >> 4, i16 = lane & 15;
    int r0 = blockIdx.y * 128 + w * 32;
    float4 ks4 = *(const float4*)(ksum + bh * 64 + 4 * i16);
    ks4.x += EPSF; ks4.y += EPSF; ks4.z += EPSF; ks4.w += EPSF;
    float qs0 = 0.f, qs1 = 0.f, qs2 = 0.f, qs3 = 0.f;
    float qa0 = 0.f, qa1 = 0.f, qa2 = 0.f, qa3 = 0.f;
#pragma unroll
    for (int ib = 0; ib < 2; ++ib) {
        float4 x[4];
#pragma unroll
        for (int j = 0; j < 4; ++j) {
            int r = r0 + (ib * 4 + j) * 4 + q4;
            x[j] = *(const float4*)(Q + (((size_t)b * L_ + r) * H_ + h) * 64 + 4 * i16);
        }
#pragma unroll
        for (int j = 0; j < 4; ++j) {
            float s0 = sigf(x[j].x), s1 = sigf(x[j].y), s2 = sigf(x[j].z), s3 = sigf(x[j].w);
            float pa = (s0 + EPSF) * ks4.x + (s1 + EPSF) * ks4.y +
                       (s2 + EPSF) * ks4.z + (s3 + EPSF) * ks4.w;
#pragma unroll
            for (int m = 1; m < 16; m <<= 1) pa += __shfl_xor(pa, m, 64);
            float nr = __builtin_amdgcn_rcpf(pa);
            qs0 += s0; qs1 += s1; qs2 += s2; qs3 += s3;
            qa0 += s0 * nr; qa1 += s1 * nr; qa2 += s2 * nr; qa3 += s3 * nr;
        }
    }
#pragma unroll
    for (int m = 16; m < 64; m <<= 1) {
        qs0 += __shfl_xor(qs0, m, 64); qs1 += __shfl_xor(qs1, m, 64);
        qs2 += __shfl_xor(qs2, m, 64); qs3 += __shfl_xor(qs3, m, 64);
        qa0 += __shfl_xor(qa0, m, 64); qa1 += __shfl_xor(qa1, m, 64);
        qa2 += __shfl_xor(qa2, m, 64); qa3 += __shfl_xor(qa3, m, 64);
    }
    if (q4 == 0) {
        atomicAdd(&qsum[bh * 64 + 4 * i16 + 0], qs0);
        atomicAdd(&qsum[bh * 64 + 4 * i16 + 1], qs1);
        atomicAdd(&qsum[bh * 64 + 4 * i16 + 2], qs2);
        atomicAdd(&qsum[bh * 64 + 4 * i16 + 3], qs3);
        atomicAdd(&qn[bh * 64 + 4 * i16 + 0], qa0);
        atomicAdd(&qn[bh * 64 + 4 * i16 + 1], qa1);
        atomicAdd(&qn[bh * 64 + 4 * i16 + 2], qa2);
        atomicAdd(&qn[bh * 64 + 4 * i16 + 3], qa3);
    }
}

// ---------------- P3: kn, den, KV-partials via MFMA ----------------
__global__ __launch_bounds__(256, 4) void k_kv(const float* __restrict__ K,
                                               const float* __restrict__ V,
                                               const float* __restrict__ qsum,
                                               const float* __restrict__ qn,
                                               float* __restrict__ kn,
                                               float* __restrict__ den,
                                               float* __restrict__ KVp) {
    int bh = blockIdx.x, b = bh >> 4, h = bh & 15;
    int t = threadIdx.x, lane = t & 63, w = t >> 6;
    int q4 = lane >> 4, i16 = lane & 15;
    __shared__ uint32_t skp[64 * STR];
    __shared__ uint32_t vwp[64 * STR];
    float4 qsE = *(const float4*)(qsum + bh * 64 + 4 * i16);
    float4 qnE = *(const float4*)(qn + bh * 64 + 4 * i16);
    qsE.x += EPSF; qsE.y += EPSF; qsE.z += EPSF; qsE.w += EPSF;
    qnE.x += EPSF; qnE.y += EPSF; qnE.z += EPSF; qnE.w += EPSF;
    f32x4 acc[4];
#pragma unroll
    for (int tm = 0; tm < 4; ++tm) acc[tm] = (f32x4){0.f, 0.f, 0.f, 0.f};
    float kn0 = 0.f, kn1 = 0.f, kn2 = 0.f, kn3 = 0.f, dacc = 0.f;
    int rowbase = blockIdx.y * 256;
    // prologue: tile 0 K/V into registers
    float4 kx[4], vx[4];
#pragma unroll
    for (int j = 0; j < 4; ++j) {
        int r = rowbase + w * 16 + j * 4 + q4;
        size_t off = (((size_t)b * L_ + r) * H_ + h) * 64 + 4 * i16;
        kx[j] = *(const float4*)(K + off);
        vx[j] = *(const float4*)(V + off);
    }
#pragma unroll
    for (int tile = 0; tile < 4; ++tile) {
        // ---- staging compute from registers; wave w owns rows [w*16, w*16+16)
#pragma unroll
        for (int j = 0; j < 4; ++j) {
            int lr = w * 16 + j * 4 + q4;
            float s0 = sigf(kx[j].x), s1 = sigf(kx[j].y), s2 = sigf(kx[j].z), s3 = sigf(kx[j].w);
            float pa = (s0 + EPSF) * qsE.x + (s1 + EPSF) * qsE.y +
                       (s2 + EPSF) * qsE.z + (s3 + EPSF) * qsE.w;
            float pc = (s0 + EPSF) * qnE.x + (s1 + EPSF) * qnE.y +
                       (s2 + EPSF) * qnE.z + (s3 + EPSF) * qnE.w;
#pragma unroll
            for (int m = 1; m < 16; m <<= 1) {
                pa += __shfl_xor(pa, m, 64);
                pc += __shfl_xor(pc, m, 64);
            }
            float ncol = __builtin_amdgcn_rcpf(pa);
            float es = __expf(pc);                 // logits O(1): no max-subtract needed
            kn0 += s0 * ncol; kn1 += s1 * ncol; kn2 += s2 * ncol; kn3 += s3 * ncol;
            if (i16 == 0) dacc += es;
            uint32_t* sp = &skp[lr * STR + 4 * i16];
            *(uint2*)sp = make_uint2(packhl(s0), packhl(s1));
            *(uint2*)(sp + 2) = make_uint2(packhl(s2), packhl(s3));
            uint32_t* vp = &vwp[lr * STR + 4 * i16];
            *(uint2*)vp = make_uint2(packhl(vx[j].x * es), packhl(vx[j].y * es));
            *(uint2*)(vp + 2) = make_uint2(packhl(vx[j].z * es), packhl(vx[j].w * es));
        }
        // ---- prefetch tile t+1 K/V: latency hides under MFMA + next staging
        float4 kx2[4], vx2[4];
        if (tile < 3) {
#pragma unroll
            for (int j = 0; j < 4; ++j) {
                int r = rowbase + (tile + 1) * 64 + w * 16 + j * 4 + q4;
                size_t off = (((size_t)b * L_ + r) * H_ + h) * 64 + 4 * i16;
                kx2[j] = *(const float4*)(K + off);
                vx2[j] = *(const float4*)(V + off);
            }
        }
        __syncthreads();
        // ---- MFMA: wave w owns e-tile tn=w; KV[d][e] += sum_row SK[row][d]*VW[row][e]
#pragma unroll
        for (int ks = 0; ks < 2; ++ks) {
            uint32_t bw[8];
#pragma unroll
            for (int j = 0; j < 8; ++j)
                bw[j] = vwp[(32 * ks + 8 * q4 + j) * STR + 16 * w + i16];
            bf16x8 bhi, blo; buildfrag(bw, bhi, blo);
#pragma unroll
            for (int tm = 0; tm < 4; ++tm) {
                uint32_t aw[8];
#pragma unroll
                for (int j = 0; j < 8; ++j)
                    aw[j] = skp[(32 * ks + 8 * q4 + j) * STR + 16 * tm + i16];
                bf16x8 ahi, alo; buildfrag(aw, ahi, alo);
                MFMA3(acc[tm], ahi, alo, bhi, blo);
            }
        }
        __syncthreads();
        if (tile < 3) {
#pragma unroll
            for (int j = 0; j < 4; ++j) { kx[j] = kx2[j]; vx[j] = vx2[j]; }
        }
    }
    // ---- KV partial: plain stores (no atomics); slice = blockIdx.y
    // D[m=d][n=e], row=(lane>>4)*4+reg, col=lane&15 (m89-verified)
    float* kvslice = KVp + ((size_t)blockIdx.y * 64 + bh) * 4096;
#pragma unroll
    for (int tm = 0; tm < 4; ++tm)
#pragma unroll
        for (int r = 0; r < 4; ++r)
            kvslice[(16 * tm + 4 * q4 + r) * 64 + 16 * w + i16] = acc[tm][r];
#pragma unroll
    for (int m = 16; m < 64; m <<= 1) {
        kn0 += __shfl_xor(kn0, m, 64); kn1 += __shfl_xor(kn1, m, 64);
        kn2 += __shfl_xor(kn2, m, 64); kn3 += __shfl_xor(kn3, m, 64);
    }
    if (q4 == 0) {
        atomicAdd(&kn[bh * 64 + 4 * i16 + 0], kn0);
        atomicAdd(&kn[bh * 64 + 4 * i16 + 1], kn1);
        atomicAdd(&kn[bh * 64 + 4 * i16 + 2], kn2);
        atomicAdd(&kn[bh * 64 + 4 * i16 + 3], kn3);
    }
#pragma unroll
    for (int m = 1; m < 64; m <<= 1) dacc += __shfl_xor(dacc, m, 64);
    if (lane == 0) atomicAdd(&den[bh], dacc);
}

// ---------------- P3b: KVg = sum over 16 partial slices ----------------
__global__ __launch_bounds__(256) void k_reduce(const float* __restrict__ KVp,
                                                float* __restrict__ KVg) {
    int bh = blockIdx.x;            // 64
    int f4 = blockIdx.y * 256 + threadIdx.x;  // float4 index in [0,1024)
    float4 acc = make_float4(0.f, 0.f, 0.f, 0.f);
#pragma unroll
    for (int p = 0; p < 16; ++p) {
        float4 x = *(const float4*)(KVp + ((size_t)p * 64 + bh) * 4096 + 4 * f4);
        acc.x += x.x; acc.y += x.y; acc.z += x.z; acc.w += x.w;
    }
    *(float4*)(KVg + (size_t)bh * 4096 + 4 * f4) = acc;
}

// ---------------- P4: out = (SQ·KV) * nrow * rref * S/den via MFMA ----------------
__global__ __launch_bounds__(256, 4) void k_out(const float* __restrict__ Q,
                                                const float* __restrict__ ksum,
                                                const float* __restrict__ kn,
                                                const float* __restrict__ den,
                                                const float* __restrict__ KVg,
                                                float* __restrict__ out) {
    int bh = blockIdx.x, b = bh >> 4, h = bh & 15;
    int t = threadIdx.x, lane = t & 63, w = t >> 6;
    int q4 = lane >> 4, i16 = lane & 15;
    __shared__ uint32_t kvt[64 * STRO];        // packed KV^T: [e][d]
    __shared__ uint32_t sqp[4][16 * STRO];     // per-wave 16-row SQ staging
    __shared__ float scale_s[4][16];
    float4 ksE = *(const float4*)(ksum + bh * 64 + 4 * i16);
    float4 knE = *(const float4*)(kn + bh * 64 + 4 * i16);
    ksE.x += EPSF; ksE.y += EPSF; ksE.z += EPSF; ksE.w += EPSF;
    knE.x += EPSF; knE.y += EPSF; knE.z += EPSF; knE.w += EPSF;
    float sden = 4096.0f * __builtin_amdgcn_rcpf(den[bh]);
    // KV^T transpose-stage, float4 global loads
#pragma unroll
    for (int i = 0; i < 4; ++i) {
        int f4 = t + i * 256;
        float4 x = *(const float4*)(KVg + (size_t)bh * 4096 + 4 * f4);
        int d = (4 * f4) & 63, e = f4 >> 4;
        kvt[(d + 0) * STRO + e] = packhl(x.x);
        kvt[(d + 1) * STRO + e] = packhl(x.y);
        kvt[(d + 2) * STRO + e] = packhl(x.z);
        kvt[(d + 3) * STRO + e] = packhl(x.w);
    }
    int rowbase = blockIdx.y * 256;
    // prologue Q loads for g=0 (overlap the kvt staging above)
    float4 qx[4];
#pragma unroll
    for (int j = 0; j < 4; ++j) {
        int r = rowbase + w * 64 + j * 4 + q4;
        qx[j] = *(const float4*)(Q + (((size_t)b * L_ + r) * H_ + h) * 64 + 4 * i16);
    }
    __syncthreads();
#pragma unroll
    for (int g = 0; g < 4; ++g) {
        int r0 = rowbase + w * 64 + g * 16;
        // ---- stage this wave's 16 rows from registers (wave-private: no barrier)
#pragma unroll
        for (int j = 0; j < 4; ++j) {
            int lr = j * 4 + q4;
            float s0 = sigf(qx[j].x), s1 = sigf(qx[j].y), s2 = sigf(qx[j].z), s3 = sigf(qx[j].w);
            float pa = (s0 + EPSF) * ksE.x + (s1 + EPSF) * ksE.y +
                       (s2 + EPSF) * ksE.z + (s3 + EPSF) * ksE.w;
            float pb = (s0 + EPSF) * knE.x + (s1 + EPSF) * knE.y +
                       (s2 + EPSF) * knE.z + (s3 + EPSF) * knE.w;
#pragma unroll
            for (int m = 1; m < 16; m <<= 1) {
                pa += __shfl_xor(pa, m, 64);
                pb += __shfl_xor(pb, m, 64);
            }
            float sc = __builtin_amdgcn_rcpf(pa) * sigf(pb) * sden;  // nrow*rref*S/den
            if (i16 == 0) scale_s[w][lr] = sc;
            uint32_t* sp = &sqp[w][lr * STRO + 4 * i16];
            *(uint4*)sp = make_uint4(packhl(s0), packhl(s1), packhl(s2), packhl(s3));
        }
        // ---- prefetch next group's Q: hides under MFMA below
        float4 qx2[4];
        if (g < 3) {
#pragma unroll
            for (int j = 0; j < 4; ++j) {
                int r = rowbase + w * 64 + (g + 1) * 16 + j * 4 + q4;
                qx2[j] = *(const float4*)(Q + (((size_t)b * L_ + r) * H_ + h) * 64 + 4 * i16);
            }
        }
        f32x4 acc[4];
#pragma unroll
        for (int tn = 0; tn < 4; ++tn) acc[tn] = (f32x4){0.f, 0.f, 0.f, 0.f};
#pragma unroll
        for (int ks = 0; ks < 2; ++ks) {
            const uint32_t* ap = &sqp[w][i16 * STRO + 32 * ks + 8 * q4];
            uint4 a0 = *(const uint4*)ap, a1 = *(const uint4*)(ap + 4);
            uint32_t aw[8] = {a0.x, a0.y, a0.z, a0.w, a1.x, a1.y, a1.z, a1.w};
            bf16x8 ahi, alo; buildfrag(aw, ahi, alo);
#pragma unroll
            for (int tn = 0; tn < 4; ++tn) {
                const uint32_t* bp = &kvt[(16 * tn + i16) * STRO + 32 * ks + 8 * q4];
                uint4 b0 = *(const uint4*)bp, b1 = *(const uint4*)(bp + 4);
                uint32_t bw[8] = {b0.x, b0.y, b0.z, b0.w, b1.x, b1.y, b1.z, b1.w};
                bf16x8 bhi, blo; buildfrag(bw, bhi, blo);
                MFMA3(acc[tn], ahi, alo, bhi, blo);
            }
        }
#pragma unroll
        for (int tn = 0; tn < 4; ++tn)
#pragma unroll
            for (int r = 0; r < 4; ++r) {
                int rl = 4 * q4 + r;
                float sc = scale_s[w][rl];
                out[(((size_t)b * L_ + (r0 + rl)) * H_ + h) * 64 + 16 * tn + i16] =
                    acc[tn][r] * sc;
            }
        if (g < 3) {
#pragma unroll
            for (int j = 0; j < 4; ++j) qx[j] = qx2[j];
        }
    }
}

extern "C" void kernel_launch(void* const* d_in, const int* in_sizes, int n_in,
                              void* d_out, int out_size, void* d_ws, size_t ws_size,
                              hipStream_t stream) {
    const float* Q = (const float*)d_in[0];
    const float* K = (const float*)d_in[1];
    const float* V = (const float*)d_in[2];
    float* out = (float*)d_out;
    float* ws = (float*)d_ws;
    float* ksum = ws;            // 4096
    float* qsum = ws + 4096;     // 4096
    float* qn   = ws + 8192;     // 4096
    float* kn   = ws + 12288;    // 4096
    float* den  = ws + 16384;    // 64
    float* KVg  = ws + 16448;    // 64*64*64 = 262144
    float* KVp  = ws + 16448 + 262144;  // 16 slices * 262144 = 4194304

    // only the small reduction buffers need zeroing (KVp/KVg fully overwritten)
    hipMemsetAsync(d_ws, 0, 16448ull * 4ull, stream);
    k_ksum<<<dim3(64, 32), 256, 0, stream>>>(K, ksum);
    k_qpass<<<dim3(64, 32), 256, 0, stream>>>(Q, ksum, qsum, qn);
    k_kv<<<dim3(64, 16), 256, 0, stream>>>(K, V, qsum, qn, kn, den, KVp);
    k_reduce<<<dim3(64, 4), 256, 0, stream>>>(KVp, KVg);
    k_out<<<dim3(64, 16), 256, 0, stream>>>(Q, ksum, kn, den, KVg, out);
}